// Round 1
// baseline (200.004 us; speedup 1.0000x reference)
//
#include <hip/hip_runtime.h>

// GRU fused kernel, MI355X/gfx950.
// B=16384, T=28, F=28, H=128, C=10. Grid 256 blocks x 256 thr (4 waves), 1 block/CU.
// Block owns 64 batch rows for all 28 steps (recurrence is per-sample independent).
// Weights packed once into LDS as bf16 MFMA B-fragments; h kept fp32 in registers
// (D-layout) + bf16 copy in LDS (A-operand source). x double-buffered, 1-step prefetch.

#define B_  16384
#define T_  28
#define F_  28
#define H_  128
#define C_  10
#define MB  64     // batch rows per block
#define LHS 136    // lh row stride in ushorts (272 B = 17*16: 16B-aligned rows, stride%32dw==4)
#define LXS 40     // lx row stride in ushorts (80 B)

typedef short  short8 __attribute__((ext_vector_type(8)));
typedef float  f32x4  __attribute__((ext_vector_type(4)));

__device__ __forceinline__ unsigned short f2bf(float f) {   // RNE fp32->bf16
    unsigned u = __builtin_bit_cast(unsigned, f);
    u += 0x7fffu + ((u >> 16) & 1u);
    return (unsigned short)(u >> 16);
}
__device__ __forceinline__ float bf2f(unsigned short h) {
    unsigned u = ((unsigned)h) << 16;
    return __builtin_bit_cast(float, u);
}
__device__ __forceinline__ float fast_sig(float x) {        // 1/(1+e^-x)
    float e = __builtin_amdgcn_exp2f(x * -1.442695040888963f);
    return __builtin_amdgcn_rcpf(1.0f + e);
}
__device__ __forceinline__ float fast_tanh(float x) {       // 1 - 2/(1+e^{2x})
    float e = __builtin_amdgcn_exp2f(x * 2.885390081777927f);
    return 1.0f - 2.0f * __builtin_amdgcn_rcpf(1.0f + e);
}

__global__ __launch_bounds__(256, 1)
void gru_fused(const float* __restrict__ x,     // (B,T,F)
               const float* __restrict__ wk,    // (F,3H) = (28,384)
               const float* __restrict__ wrk,   // (H,3H) = (128,384)
               const float* __restrict__ bias,  // (2,3H)
               const float* __restrict__ dw,    // (H,C)
               const float* __restrict__ db,    // (C,)
               float* __restrict__ out)         // (B,C)
{
    // ---- LDS (total 160320 B) ----
    __shared__ __align__(16) unsigned short lwB[24*4*512]; // W_r B-frags: [ct 0..23][kb 0..3][lane][8]
    __shared__ __align__(16) unsigned short lwX[24*512];   // kernel B-frags (K padded 28->32): [ct][lane][8]
    __shared__ __align__(16) unsigned short lh[MB*LHS];    // h bf16, row-major padded
    __shared__ __align__(16) unsigned short lx[2][MB*LXS]; // x_t bf16 staging, double-buffered
    __shared__ float lbias[512];   // [0..255]=bi+br (z,r cols), [256..383]=bi_h, [384..511]=br_h
    __shared__ float ldw[H_*C_];
    __shared__ float ldb[16];
    __shared__ float llog[MB][C_];

    const int tid  = threadIdx.x;
    const int base = blockIdx.x * MB;

    // ---- pack W_r fragments: elem(lane,j) = W[k=kb*32+(lane>>4)*8+j][col=ct*16+(lane&15)]
    for (int i = tid; i < 24*4*64; i += 256) {
        int fi = i >> 6, ln = i & 63;
        int ct = fi >> 2, kb = fi & 3;
        int col = ct*16 + (ln & 15);
        int k0  = kb*32 + (ln >> 4)*8;
        #pragma unroll
        for (int j = 0; j < 8; ++j)
            lwB[i*8 + j] = f2bf(wrk[(k0 + j)*384 + col]);
    }
    // ---- pack input-kernel fragments (zeros for k>=28)
    for (int i = tid; i < 24*64; i += 256) {
        int ct = i >> 6, ln = i & 63;
        int col = ct*16 + (ln & 15);
        int k0  = (ln >> 4)*8;
        #pragma unroll
        for (int j = 0; j < 8; ++j) {
            int k = k0 + j;
            lwX[i*8 + j] = (k < F_) ? f2bf(wk[k*384 + col]) : (unsigned short)0;
        }
    }
    // ---- biases / dense weights
    if (tid < 256) lbias[tid] = bias[tid] + bias[384 + tid];
    if (tid < 128) { lbias[256+tid] = bias[256+tid]; lbias[384+tid] = bias[640+tid]; }
    for (int i = tid; i < H_*C_; i += 256) ldw[i] = dw[i];
    if (tid < C_) ldb[tid] = db[tid];
    // ---- h0 = 0
    for (int i = tid; i < MB*LHS/2; i += 256) ((unsigned*)lh)[i] = 0u;
    // ---- stage x_0
    {
        int row = tid >> 2, cb = tid & 3;
        const float* src = x + (size_t)(base + row)*(T_*F_) + cb*8;
        float4 a = *(const float4*)src;
        float4 b = (cb < 3) ? *(const float4*)(src + 4) : make_float4(0.f,0.f,0.f,0.f);
        short8 v;
        v[0]=(short)f2bf(a.x); v[1]=(short)f2bf(a.y); v[2]=(short)f2bf(a.z); v[3]=(short)f2bf(a.w);
        v[4]=(short)f2bf(b.x); v[5]=(short)f2bf(b.y); v[6]=(short)f2bf(b.z); v[7]=(short)f2bf(b.w);
        *(short8*)&lx[0][row*LXS + cb*8] = v;
    }

    // ---- wave tiling: wave=(wr_,wc_): rows [wr_*32,+32), u-half [wc_*64,+64) per gate
    const int lane = tid & 63;
    const int wave = tid >> 6;
    const int wr_  = wave & 1;
    const int wc_  = wave >> 1;
    const int n    = lane & 15;   // MFMA: A row / D col
    const int q    = lane >> 4;   // MFMA quad

    f32x4 acc[4][2][4];           // [set z,r,xh,rh][mt][ut]
    float hm[2][4][4];            // fp32 h master, D-layout
    #pragma unroll
    for (int mt = 0; mt < 2; ++mt)
        #pragma unroll
        for (int ut = 0; ut < 4; ++ut)
            #pragma unroll
            for (int r = 0; r < 4; ++r) hm[mt][ut][r] = 0.f;

    for (int t = 0; t < T_; ++t) {
        __syncthreads();   // prev-step lh/lx writes (or init) visible

        // A-fragments: h rows (own 32 rows), A[m=lane&15][k=q*8+j]
        short8 ha[2][4], xa[2];
        #pragma unroll
        for (int mt = 0; mt < 2; ++mt) {
            int rbase = (wr_*32 + mt*16 + n)*LHS;
            #pragma unroll
            for (int kb = 0; kb < 4; ++kb)
                ha[mt][kb] = *(const short8*)&lh[rbase + kb*32 + q*8];
            xa[mt] = *(const short8*)&lx[t & 1][(wr_*32 + mt*16 + n)*LXS + q*8];
        }
        // prefetch x_{t+1} (lands during compute)
        float4 pa = make_float4(0.f,0.f,0.f,0.f), pb = pa;
        const int prow = tid >> 2, pcb = tid & 3;
        if (t + 1 < T_) {
            const float* src = x + (size_t)(base + prow)*(T_*F_) + (t+1)*F_ + pcb*8;
            pa = *(const float4*)src;
            if (pcb < 3) pb = *(const float4*)(src + 4);
        }
        __syncthreads();   // all reads done; safe to overwrite lh at end of step

        // init accumulators with biases (col u = wc_*64 + ut*16 + n, same for all 4 regs)
        #pragma unroll
        for (int ut = 0; ut < 4; ++ut) {
            int u = wc_*64 + ut*16 + n;
            float bz = lbias[u], br = lbias[128+u], bx = lbias[256+u], bh = lbias[384+u];
            #pragma unroll
            for (int mt = 0; mt < 2; ++mt) {
                acc[0][mt][ut] = (f32x4){bz,bz,bz,bz};
                acc[1][mt][ut] = (f32x4){br,br,br,br};
                acc[2][mt][ut] = (f32x4){bx,bx,bx,bx};
                acc[3][mt][ut] = (f32x4){bh,bh,bh,bh};
            }
        }
        // MFMA: 120 x 16x16x32 per wave per step
        #pragma unroll
        for (int ut = 0; ut < 4; ++ut) {
            int ctz = wc_*4 + ut;
            #pragma unroll
            for (int kb = 0; kb < 4; ++kb) {
                short8 bz = *(const short8*)&lwB[(( ctz     *4 + kb)*64 + lane)*8];
                short8 br = *(const short8*)&lwB[(((8 +ctz)*4 + kb)*64 + lane)*8];
                short8 bh = *(const short8*)&lwB[(((16+ctz)*4 + kb)*64 + lane)*8];
                #pragma unroll
                for (int mt = 0; mt < 2; ++mt) {
                    acc[0][mt][ut] = __builtin_amdgcn_mfma_f32_16x16x32_bf16(ha[mt][kb], bz, acc[0][mt][ut], 0,0,0);
                    acc[1][mt][ut] = __builtin_amdgcn_mfma_f32_16x16x32_bf16(ha[mt][kb], br, acc[1][mt][ut], 0,0,0);
                    acc[3][mt][ut] = __builtin_amdgcn_mfma_f32_16x16x32_bf16(ha[mt][kb], bh, acc[3][mt][ut], 0,0,0);
                }
            }
            short8 xz = *(const short8*)&lwX[(( ctz    )*64 + lane)*8];
            short8 xr = *(const short8*)&lwX[((8 + ctz )*64 + lane)*8];
            short8 xh = *(const short8*)&lwX[((16 + ctz)*64 + lane)*8];
            #pragma unroll
            for (int mt = 0; mt < 2; ++mt) {
                acc[0][mt][ut] = __builtin_amdgcn_mfma_f32_16x16x32_bf16(xa[mt], xz, acc[0][mt][ut], 0,0,0);
                acc[1][mt][ut] = __builtin_amdgcn_mfma_f32_16x16x32_bf16(xa[mt], xr, acc[1][mt][ut], 0,0,0);
                acc[2][mt][ut] = __builtin_amdgcn_mfma_f32_16x16x32_bf16(xa[mt], xh, acc[2][mt][ut], 0,0,0);
            }
        }
        // gates + h update; D layout: row = q*4+reg, col = n
        #pragma unroll
        for (int ut = 0; ut < 4; ++ut) {
            int u = wc_*64 + ut*16 + n;
            #pragma unroll
            for (int mt = 0; mt < 2; ++mt) {
                int rowb = wr_*32 + mt*16 + q*4;
                #pragma unroll
                for (int reg = 0; reg < 4; ++reg) {
                    float z  = fast_sig(acc[0][mt][ut][reg]);
                    float r  = fast_sig(acc[1][mt][ut][reg]);
                    float hh = fast_tanh(acc[2][mt][ut][reg] + r * acc[3][mt][ut][reg]);
                    float hp = hm[mt][ut][reg];
                    float hn = hh + z * (hp - hh);
                    hm[mt][ut][reg] = hn;
                    lh[(rowb + reg)*LHS + u] = f2bf(hn);
                }
            }
        }
        // commit prefetched x into the other buffer
        if (t + 1 < T_) {
            short8 v;
            v[0]=(short)f2bf(pa.x); v[1]=(short)f2bf(pa.y); v[2]=(short)f2bf(pa.z); v[3]=(short)f2bf(pa.w);
            v[4]=(short)f2bf(pb.x); v[5]=(short)f2bf(pb.y); v[6]=(short)f2bf(pb.z); v[7]=(short)f2bf(pb.w);
            *(short8*)&lx[(t+1)&1][prow*LXS + pcb*8] = v;
        }
    }

    // ---- dense + softmax epilogue
    __syncthreads();
    {
        int row = tid >> 2, qq = tid & 3;
        for (int c = qq; c < C_; c += 4) {
            float s = ldb[c];
            #pragma unroll
            for (int u0 = 0; u0 < H_; u0 += 8) {
                short8 hv = *(const short8*)&lh[row*LHS + u0];
                #pragma unroll
                for (int j = 0; j < 8; ++j)
                    s += bf2f((unsigned short)hv[j]) * ldw[(u0+j)*C_ + c];
            }
            llog[row][c] = s;
        }
    }
    __syncthreads();
    if (tid < MB) {
        int row = tid;
        float m = llog[row][0];
        #pragma unroll
        for (int c = 1; c < C_; ++c) m = fmaxf(m, llog[row][c]);
        float e[C_], s = 0.f;
        #pragma unroll
        for (int c = 0; c < C_; ++c) {
            e[c] = __builtin_amdgcn_exp2f((llog[row][c] - m) * 1.442695040888963f);
            s += e[c];
        }
        float inv = __builtin_amdgcn_rcpf(s);
        float* o = out + (size_t)(base + row)*C_;
        #pragma unroll
        for (int c = 0; c < C_; ++c) o[c] = e[c] * inv;
    }
}

extern "C" void kernel_launch(void* const* d_in, const int* in_sizes, int n_in,
                              void* d_out, int out_size, void* d_ws, size_t ws_size,
                              hipStream_t stream) {
    const float* x   = (const float*)d_in[0];
    const float* wk  = (const float*)d_in[1];
    const float* wrk = (const float*)d_in[2];
    const float* bs  = (const float*)d_in[3];
    const float* dw  = (const float*)d_in[4];
    const float* db  = (const float*)d_in[5];
    (void)in_sizes; (void)n_in; (void)out_size; (void)d_ws; (void)ws_size;
    gru_fused<<<dim3(B_/MB), dim3(256), 0, stream>>>(x, wk, wrk, bs, dw, db, (float*)d_out);
}

// Round 2
// 165.341 us; speedup vs baseline: 1.2096x; 1.2096x over previous
//
#include <hip/hip_runtime.h>

// GRU fused, MI355X/gfx950 — round 2.
// Key change vs r1: loop-invariant weights live in REGISTERS (120 VGPR/wave),
// not LDS. LDS shrinks 160KB -> ~23KB, enabling MB=32 / grid=512 / 2 blocks/CU
// (8 waves/CU = 2 waves/SIMD) so blocks desync and MFMA/trans/LDS phases overlap.
// Per-step LDS is only the h exchange (D-layout -> A-layout) + x staging.

#define B_  16384
#define T_  28
#define F_  28
#define H_  128
#define C_  10
#define MB  32     // batch rows per block
#define LHS 136    // lh row stride in ushorts (272 B: 16B-aligned, dword-stride 68 == 4 mod 32 -> 2-way = free)
#define LXS 40     // lx row stride in ushorts (80 B)

typedef short  short8  __attribute__((ext_vector_type(8)));
typedef short  short4v __attribute__((ext_vector_type(4)));
typedef float  f32x4   __attribute__((ext_vector_type(4)));

__device__ __forceinline__ unsigned short f2bf(float f) {   // RNE fp32->bf16
    unsigned u = __builtin_bit_cast(unsigned, f);
    u += 0x7fffu + ((u >> 16) & 1u);
    return (unsigned short)(u >> 16);
}
__device__ __forceinline__ float bf2f(unsigned short h) {
    unsigned u = ((unsigned)h) << 16;
    return __builtin_bit_cast(float, u);
}
__device__ __forceinline__ float fast_sig(float x) {        // 1/(1+e^-x)
    float e = __builtin_amdgcn_exp2f(x * -1.442695040888963f);
    return __builtin_amdgcn_rcpf(1.0f + e);
}
__device__ __forceinline__ float fast_tanh(float x) {       // 1 - 2/(1+e^{2x})
    float e = __builtin_amdgcn_exp2f(x * 2.885390081777927f);
    return 1.0f - 2.0f * __builtin_amdgcn_rcpf(1.0f + e);
}

__global__ __launch_bounds__(256, 2)
void gru_fused(const float* __restrict__ x,     // (B,T,F)
               const float* __restrict__ wk,    // (F,3H) = (28,384)
               const float* __restrict__ wrk,   // (H,3H) = (128,384)
               const float* __restrict__ bias,  // (2,3H)
               const float* __restrict__ dw,    // (H,C)
               const float* __restrict__ db,    // (C,)
               float* __restrict__ out)         // (B,C)
{
    // ---- LDS (~22.5 KB) ----
    __shared__ __align__(16) unsigned short lh[MB*LHS];    // h bf16, row-major padded
    __shared__ __align__(16) unsigned short lx[2][MB*LXS]; // x_t bf16 staging, double-buffered
    __shared__ float lbias[512];   // [0..255]=bi+br (z,r), [256..383]=bi_h, [384..511]=br_h
    __shared__ float ldw[H_*C_];
    __shared__ float ldb[16];
    __shared__ float llog[MB][C_];

    const int tid  = threadIdx.x;
    const int base = blockIdx.x * MB;
    const int lane = tid & 63;
    const int wc   = tid >> 6;    // wave id -> column quarter
    const int n    = lane & 15;   // MFMA: A row / D col
    const int q    = lane >> 4;   // MFMA quad

    // ---- loop-invariant weight fragments -> REGISTERS ----
    // B-frag layout (verified r1): elem(lane,j) = W[k = kb*32 + q*8 + j][col], col = colb+ut*16+n
    short8 wz[2][4], wr[2][4], wh[2][4];   // W_r per [ut][kb], gates z/r/h: 96 VGPR
    short8 xz[2], xr[2], xh[2];            // kernel per [ut] (K pad 28->32): 24 VGPR
    {
        const int colb = wc * 32;
        #pragma unroll
        for (int ut = 0; ut < 2; ++ut) {
            const int col = colb + ut*16 + n;
            #pragma unroll
            for (int kb = 0; kb < 4; ++kb) {
                const int k0 = kb*32 + q*8;
                short8 vz, vr, vh;
                #pragma unroll
                for (int j = 0; j < 8; ++j) {
                    const float* wp = wrk + (size_t)(k0 + j)*384 + col;
                    vz[j] = (short)f2bf(wp[0]);
                    vr[j] = (short)f2bf(wp[128]);
                    vh[j] = (short)f2bf(wp[256]);
                }
                wz[ut][kb] = vz; wr[ut][kb] = vr; wh[ut][kb] = vh;
            }
            short8 vz, vr, vh;
            #pragma unroll
            for (int j = 0; j < 8; ++j) {
                const int k = q*8 + j;
                if (k < F_) {
                    const float* wp = wk + (size_t)k*384 + col;
                    vz[j] = (short)f2bf(wp[0]);
                    vr[j] = (short)f2bf(wp[128]);
                    vh[j] = (short)f2bf(wp[256]);
                } else { vz[j] = 0; vr[j] = 0; vh[j] = 0; }
            }
            xz[ut] = vz; xr[ut] = vr; xh[ut] = vh;
        }
    }

    // ---- biases / dense weights / h0 / x0 ----
    lbias[tid] = bias[tid] + bias[384 + tid];              // z,r cols 0..255
    if (tid < 128) { lbias[256+tid] = bias[256+tid]; lbias[384+tid] = bias[640+tid]; }
    for (int i = tid; i < H_*C_; i += 256) ldw[i] = dw[i];
    if (tid < C_) ldb[tid] = db[tid];
    for (int i = tid; i < MB*LHS/2; i += 256) ((unsigned*)lh)[i] = 0u;
    {
        const int row = tid >> 3, seg = tid & 7;
        short4v v = (short4v){0,0,0,0};
        if (seg < 7) {
            float4 a = *(const float4*)(x + (size_t)(base + row)*(T_*F_) + seg*4);
            v[0]=(short)f2bf(a.x); v[1]=(short)f2bf(a.y); v[2]=(short)f2bf(a.z); v[3]=(short)f2bf(a.w);
        }
        *(short4v*)&lx[0][row*LXS + seg*4] = v;
    }

    float hm[2][2][4];            // fp32 h master, D-layout [mt][ut][reg]
    #pragma unroll
    for (int mt = 0; mt < 2; ++mt)
        #pragma unroll
        for (int ut = 0; ut < 2; ++ut)
            #pragma unroll
            for (int r = 0; r < 4; ++r) hm[mt][ut][r] = 0.f;

    for (int t = 0; t < T_; ++t) {
        __syncthreads();   // prev-step lh/lx writes (or init) visible

        // A-fragments (same rows for all 4 waves): A[m=n][k=q*8+j]
        short8 ha[2][4], xav[2];
        #pragma unroll
        for (int mt = 0; mt < 2; ++mt) {
            const int rbase = (mt*16 + n)*LHS;
            #pragma unroll
            for (int kb = 0; kb < 4; ++kb)
                ha[mt][kb] = *(const short8*)&lh[rbase + kb*32 + q*8];
            xav[mt] = *(const short8*)&lx[t & 1][(mt*16 + n)*LXS + q*8];
        }
        // global prefetch of x_{t+1}
        float4 pa = make_float4(0.f,0.f,0.f,0.f);
        const int prow = tid >> 3, pseg = tid & 7;
        const bool pv = (t + 1 < T_);
        if (pv && pseg < 7)
            pa = *(const float4*)(x + (size_t)(base + prow)*(T_*F_) + (t+1)*F_ + pseg*4);
        __syncthreads();   // all reads done; safe to overwrite lh

        #pragma unroll
        for (int ut = 0; ut < 2; ++ut) {
            const int u = wc*32 + ut*16 + n;
            const float bz = lbias[u], br = lbias[128+u], bx = lbias[256+u], bh = lbias[384+u];
            f32x4 az[2], ar[2], ax[2], ah[2];
            #pragma unroll
            for (int mt = 0; mt < 2; ++mt) {
                az[mt] = (f32x4){bz,bz,bz,bz};
                ar[mt] = (f32x4){br,br,br,br};
                ax[mt] = (f32x4){bx,bx,bx,bx};
                ah[mt] = (f32x4){bh,bh,bh,bh};
            }
            #pragma unroll
            for (int kb = 0; kb < 4; ++kb)
                #pragma unroll
                for (int mt = 0; mt < 2; ++mt) {
                    az[mt] = __builtin_amdgcn_mfma_f32_16x16x32_bf16(ha[mt][kb], wz[ut][kb], az[mt], 0,0,0);
                    ar[mt] = __builtin_amdgcn_mfma_f32_16x16x32_bf16(ha[mt][kb], wr[ut][kb], ar[mt], 0,0,0);
                    ah[mt] = __builtin_amdgcn_mfma_f32_16x16x32_bf16(ha[mt][kb], wh[ut][kb], ah[mt], 0,0,0);
                }
            #pragma unroll
            for (int mt = 0; mt < 2; ++mt) {
                az[mt] = __builtin_amdgcn_mfma_f32_16x16x32_bf16(xav[mt], xz[ut], az[mt], 0,0,0);
                ar[mt] = __builtin_amdgcn_mfma_f32_16x16x32_bf16(xav[mt], xr[ut], ar[mt], 0,0,0);
                ax[mt] = __builtin_amdgcn_mfma_f32_16x16x32_bf16(xav[mt], xh[ut], ax[mt], 0,0,0);
            }
            // gates + h update; D layout: row = q*4+reg, col = n
            #pragma unroll
            for (int mt = 0; mt < 2; ++mt) {
                const int rowb = mt*16 + q*4;
                #pragma unroll
                for (int reg = 0; reg < 4; ++reg) {
                    float z  = fast_sig(az[mt][reg]);
                    float r  = fast_sig(ar[mt][reg]);
                    float hh = fast_tanh(ax[mt][reg] + r * ah[mt][reg]);
                    float hp = hm[mt][ut][reg];
                    float hn = hh + z * (hp - hh);
                    hm[mt][ut][reg] = hn;
                    lh[(rowb + reg)*LHS + u] = f2bf(hn);
                }
            }
        }
        // commit prefetched x into the other parity buffer
        if (pv) {
            short4v v = (short4v){0,0,0,0};
            if (pseg < 7) {
                v[0]=(short)f2bf(pa.x); v[1]=(short)f2bf(pa.y);
                v[2]=(short)f2bf(pa.z); v[3]=(short)f2bf(pa.w);
            }
            *(short4v*)&lx[(t+1)&1][prow*LXS + pseg*4] = v;
        }
    }

    // ---- dense + softmax epilogue ----
    __syncthreads();
    if (tid < 128) {
        const int row = tid >> 2, qq = tid & 3;
        for (int c = qq; c < C_; c += 4) {
            float s = ldb[c];
            #pragma unroll
            for (int u0 = 0; u0 < H_; u0 += 8) {
                short8 hv = *(const short8*)&lh[row*LHS + u0];
                #pragma unroll
                for (int j = 0; j < 8; ++j)
                    s += bf2f((unsigned short)hv[j]) * ldw[(u0+j)*C_ + c];
            }
            llog[row][c] = s;
        }
    }
    __syncthreads();
    if (tid < MB) {
        const int row = tid;
        float m = llog[row][0];
        #pragma unroll
        for (int c = 1; c < C_; ++c) m = fmaxf(m, llog[row][c]);
        float e[C_], s = 0.f;
        #pragma unroll
        for (int c = 0; c < C_; ++c) {
            e[c] = __builtin_amdgcn_exp2f((llog[row][c] - m) * 1.442695040888963f);
            s += e[c];
        }
        const float inv = __builtin_amdgcn_rcpf(s);
        float* o = out + (size_t)(base + row)*C_;
        #pragma unroll
        for (int c = 0; c < C_; ++c) o[c] = e[c] * inv;
    }
}

extern "C" void kernel_launch(void* const* d_in, const int* in_sizes, int n_in,
                              void* d_out, int out_size, void* d_ws, size_t ws_size,
                              hipStream_t stream) {
    const float* x   = (const float*)d_in[0];
    const float* wk  = (const float*)d_in[1];
    const float* wrk = (const float*)d_in[2];
    const float* bs  = (const float*)d_in[3];
    const float* dw  = (const float*)d_in[4];
    const float* db  = (const float*)d_in[5];
    (void)in_sizes; (void)n_in; (void)out_size; (void)d_ws; (void)ws_size;
    gru_fused<<<dim3(B_/MB), dim3(256), 0, stream>>>(x, wk, wrk, bs, dw, db, (float*)d_out);
}